// Round 11
// baseline (115.554 us; speedup 1.0000x reference)
//
#include <hip/hip_runtime.h>
#include <hip/hip_bf16.h>

// Problem constants
#define B_  8
#define CIN 32
#define COUT 16
#define K_  4
#define HID 9
#define HIN 256
#define WIN 256
#define HW  (HIN * WIN)
#define HOUT 512
#define WOUT 512
#define TEMP 34.0f
#define EPS_ 1e-5f

#define SROWS 18          // slab rows: 16 bases + 2 halo
#define SLAB  624         // dwords per channel-pair slab: 18*34=612, padded
                          // so SLAB%32==16 -> lane-group aliasing 2-way (free)

typedef float f32x4 __attribute__((ext_vector_type(4)));
typedef __fp16 fp16x2 __attribute__((ext_vector_type(2)));
typedef __fp16 f16x8 __attribute__((ext_vector_type(8)));

union FragB { unsigned u[4]; f16x8 h; };

__device__ inline unsigned pk2(float a, float b) {
    union { fp16x2 f; unsigned u; } x;
    x.f = __builtin_amdgcn_cvt_pkrtz(a, b);  // a -> low half, b -> high half
    return x.u;
}
__device__ inline unsigned short f16b(float v) {
    union { __fp16 h; unsigned short u; } x;
    x.h = (__fp16)v;
    return x.u;
}

// ---------------------------------------------------------------------------
// Kernel A: pooled[b][c] = mean over HxW of x[b][c]  (== mean of upsampled)
// 1024 threads/block -> 4 waves/SIMD for latency hiding.
// ---------------------------------------------------------------------------
__global__ __launch_bounds__(1024) void pool_kernel(const float* __restrict__ x,
                                                    float* __restrict__ pooled) {
    int bc = blockIdx.x;  // 0..255  (b*32+c)
    const float4* p = (const float4*)(x + (size_t)bc * HW);
    float s = 0.f;
    for (int i = threadIdx.x; i < HW / 4; i += 1024) {
        float4 v = p[i];
        s += v.x + v.y + v.z + v.w;
    }
    #pragma unroll
    for (int off = 32; off > 0; off >>= 1) s += __shfl_down(s, off);
    __shared__ float red[16];
    if ((threadIdx.x & 63) == 0) red[threadIdx.x >> 6] = s;
    __syncthreads();
    if (threadIdx.x < 16) {
        float t = red[threadIdx.x];
        t += __shfl_down(t, 8);
        t += __shfl_down(t, 4);
        t += __shfl_down(t, 2);
        t += __shfl_down(t, 1);
        if (threadIdx.x == 0) pooled[bc] = t * (1.f / HW);
    }
}

// ---------------------------------------------------------------------------
// Kernel B: attention -> aggregated, BN-folded, parity-combined 2x2 weights,
// packed f16 in the MFMA A-fragment layout:
// ushort index = (((b*16 + par*4 + ks)*64 + (g*16+o))*4 + tap)*2 + (i&1)
// with ks = i>>3, g = (i>>1)&3  (channel-pair halves, tap-per-dword).
// A and B fragments share the same (lane-group, dword, half) -> k map, so
// any hardware k-permutation cancels as long as both sides use this layout.
// ---------------------------------------------------------------------------
__global__ __launch_bounds__(256) void attn_weights_kernel(
    const float* __restrict__ pooled, const float* __restrict__ weight,
    const float* __restrict__ bias, const float* __restrict__ fc1_w,
    const float* __restrict__ fc2_w, const float* __restrict__ fc2_b,
    const float* __restrict__ gamma, const float* __restrict__ beta,
    const float* __restrict__ mean, const float* __restrict__ var,
    unsigned short* __restrict__ wpk16, float* __restrict__ bias_eff) {
    int b = blockIdx.x;
    __shared__ float attn[K_];
    if (threadIdx.x == 0) {
        const float* pb = pooled + b * CIN;
        float h[HID];
        for (int j = 0; j < HID; ++j) {
            float s = 0.f;
            for (int c = 0; c < CIN; ++c) s += pb[c] * fc1_w[j * CIN + c];
            h[j] = fmaxf(s, 0.f);
        }
        float lg[K_];
        float mx = -1e30f;
        for (int k = 0; k < K_; ++k) {
            float s = fc2_b[k];
            for (int j = 0; j < HID; ++j) s += h[j] * fc2_w[k * HID + j];
            lg[k] = s * (1.f / TEMP);
            mx = fmaxf(mx, lg[k]);
        }
        float den = 0.f;
        for (int k = 0; k < K_; ++k) { lg[k] = expf(lg[k] - mx); den += lg[k]; }
        for (int k = 0; k < K_; ++k) attn[k] = lg[k] / den;
    }
    __syncthreads();
    float a0 = attn[0], a1 = attn[1], a2 = attn[2], a3v = attn[3];

    for (int p = threadIdx.x; p < COUT * CIN; p += 256) {
        int o = p >> 5, i = p & 31;
        float scale = gamma[o] / sqrtf(var[o] + EPS_);
        const float* w0 = weight + ((size_t)(0 * COUT + o) * CIN + i) * 9;
        const int kstr = COUT * CIN * 9;  // 4608
        float a3w[9];
        #pragma unroll
        for (int t = 0; t < 9; ++t)
            a3w[t] = scale * (a0 * w0[t] + a1 * w0[kstr + t] +
                              a2 * w0[2 * kstr + t] + a3v * w0[3 * kstr + t]);
        float tmp[2][2][3];
        #pragma unroll
        for (int kx = 0; kx < 3; ++kx) {
            tmp[0][0][kx] = a3w[0 * 3 + kx];
            tmp[0][1][kx] = a3w[1 * 3 + kx] + a3w[2 * 3 + kx];
            tmp[1][0][kx] = a3w[0 * 3 + kx] + a3w[1 * 3 + kx];
            tmp[1][1][kx] = a3w[2 * 3 + kx];
        }
        float w16[16];  // [par(py,px)][tap(u,v)] = [par*4 + u*2+v]
        #pragma unroll
        for (int py = 0; py < 2; ++py)
            #pragma unroll
            for (int px = 0; px < 2; ++px)
                #pragma unroll
                for (int u = 0; u < 2; ++u)
                    #pragma unroll
                    for (int v = 0; v < 2; ++v) {
                        const float* t = tmp[py][u];
                        float val = (px == 0) ? (v == 0 ? t[0] : t[1] + t[2])
                                              : (v == 0 ? t[0] + t[1] : t[2]);
                        w16[(py * 2 + px) * 4 + u * 2 + v] = val;
                    }
        const int ks = i >> 3, g = (i >> 1) & 3, hf = i & 1;
        const int l = g * 16 + o;
        #pragma unroll
        for (int par = 0; par < 4; ++par)
            #pragma unroll
            for (int d = 0; d < 4; ++d)
                wpk16[(((size_t)(b * 16 + par * 4 + ks) * 64 + l) * 4 + d) * 2 +
                      hf] = f16b(w16[par * 4 + d]);
    }
    if (threadIdx.x < COUT) {
        int o = threadIdx.x;
        float scale = gamma[o] / sqrtf(var[o] + EPS_);
        float shift = beta[o] - mean[o] * scale;
        float s = a0 * bias[0 * COUT + o] + a1 * bias[1 * COUT + o] +
                  a2 * bias[2 * COUT + o] + a3v * bias[3 * COUT + o];
        bias_eff[b * COUT + o] = s * scale + shift;
    }
}

// ---------------------------------------------------------------------------
// Kernel C: fused upsample+conv+BN+ReLU via MFMA (16x16x32 f16).
// Block: (b, 16x32 input-base tile) -> 32x64 outputs x 16 o. LDS 39.9 KB
// (16 ch-pair slabs x 18x34, zero-padded halo) -> 3-4 blocks/CU.
// Wave w owns base rows 4w..4w+3; per (column-half, row-pair, K-step):
// load the 4x3 dword window once, feed 2 rows x 4 parity MFMAs.
// acc[2][4] = 32 VGPRs -> no spill. px-paired float2 stores.
// ---------------------------------------------------------------------------
__global__ __launch_bounds__(256) void conv_kernel(
    const float* __restrict__ x, const unsigned* __restrict__ wpk,
    const float* __restrict__ bias_eff, float* __restrict__ out) {
    const int tile = blockIdx.x;   // 0..127
    const int b = blockIdx.y;      // 0..7
    const int r0 = (tile >> 3) * 16, c0 = (tile & 7) * 32;
    const int tid = threadIdx.x;

    __shared__ unsigned lds32[16 * SLAB];  // 39,936 B

    const int w = tid >> 6, lane = tid & 63;
    const int g = lane >> 4, n = lane & 15;

    // A fragments [par][ks]: issue global loads first (overlap with staging)
    f16x8 areg[4][4];
    {
        const f16x8* wp = (const f16x8*)wpk + (size_t)b * 1024 + lane;
        #pragma unroll
        for (int par = 0; par < 4; ++par)
            #pragma unroll
            for (int ks = 0; ks < 4; ++ks)
                areg[par][ks] = wp[(par * 4 + ks) * 64];
    }

    const float* xb = x + (size_t)b * CIN * HW;

    // ---- stage: channel-pair f16 packing, zero-padded halo ----
    for (int i2 = 0; i2 < 16; ++i2) {
        const float* p0 = xb + (size_t)(2 * i2) * HW;
        for (int e = tid; e < SROWS * 34; e += 256) {
            int pr = e / 34, pc = e - pr * 34;
            int gr = r0 - 1 + pr, gc = c0 - 1 + pc;
            bool ok = ((unsigned)gr < (unsigned)HIN) &
                      ((unsigned)gc < (unsigned)WIN);
            int off = ok ? (gr * WIN + gc) : 0;
            float v0 = p0[off];
            float v1 = p0[off + HW];
            if (!ok) { v0 = 0.f; v1 = 0.f; }
            lds32[i2 * SLAB + e] = pk2(v0, v1);
        }
    }
    __syncthreads();

    float bias4[4];
    #pragma unroll
    for (int q = 0; q < 4; ++q) bias4[q] = bias_eff[b * COUT + g * 4 + q];

    // wave w owns base rows w*4 .. w*4+3: 2 column halves x 2 row pairs
    for (int h = 0; h < 2; ++h) {
        #pragma unroll
        for (int p2 = 0; p2 < 2; ++p2) {
            const int rA = w * 4 + p2 * 2;  // first base row of the pair

            f32x4 acc[2][4];
            #pragma unroll
            for (int rr = 0; rr < 2; ++rr)
                #pragma unroll
                for (int par = 0; par < 4; ++par)
                    acc[rr][par] = (f32x4){0.f, 0.f, 0.f, 0.f};

            #pragma unroll
            for (int ks = 0; ks < 4; ++ks) {
                const int base = (ks * 4 + g) * SLAB + rA * 34 + (h << 4) + n;
                unsigned nb[4][3];  // 4-row x 3-col window, shared by 2 rows
                #pragma unroll
                for (int rr = 0; rr < 4; ++rr)
                    #pragma unroll
                    for (int dv = 0; dv < 3; ++dv)
                        nb[rr][dv] = lds32[base + rr * 34 + dv];
                #pragma unroll
                for (int rr = 0; rr < 2; ++rr)
                    #pragma unroll
                    for (int par = 0; par < 4; ++par) {
                        const int py = par >> 1, px = par & 1;
                        FragB bf;
                        bf.u[0] = nb[rr + py][px];
                        bf.u[1] = nb[rr + py][px + 1];
                        bf.u[2] = nb[rr + py + 1][px];
                        bf.u[3] = nb[rr + py + 1][px + 1];
                        acc[rr][par] = __builtin_amdgcn_mfma_f32_16x16x32_f16(
                            areg[par][ks], bf.h, acc[rr][par], 0, 0, 0);
                    }
            }

            // epilogue: bias + ReLU, px-paired float2 stores
            #pragma unroll
            for (int rr = 0; rr < 2; ++rr) {
                #pragma unroll
                for (int py = 0; py < 2; ++py) {
                    const int y = 2 * (r0 + rA + rr) + py;
                    #pragma unroll
                    for (int q = 0; q < 4; ++q) {
                        float2 st;
                        st.x = fmaxf(acc[rr][2 * py + 0][q] + bias4[q], 0.f);
                        st.y = fmaxf(acc[rr][2 * py + 1][q] + bias4[q], 0.f);
                        *(float2*)&out[((size_t)(b * COUT + g * 4 + q) * HOUT +
                                        y) * WOUT +
                                       2 * (c0 + (h << 4) + n)] = st;
                    }
                }
            }
        }
    }
}

extern "C" void kernel_launch(void* const* d_in, const int* in_sizes, int n_in,
                              void* d_out, int out_size, void* d_ws, size_t ws_size,
                              hipStream_t stream) {
    const float* x      = (const float*)d_in[0];
    const float* weight = (const float*)d_in[1];
    const float* bias   = (const float*)d_in[2];
    const float* fc1_w  = (const float*)d_in[3];
    const float* fc2_w  = (const float*)d_in[4];
    const float* fc2_b  = (const float*)d_in[5];
    const float* bn_g   = (const float*)d_in[6];
    const float* bn_b   = (const float*)d_in[7];
    const float* bn_m   = (const float*)d_in[8];
    const float* bn_v   = (const float*)d_in[9];
    float* out = (float*)d_out;

    float* ws = (float*)d_ws;
    float*    pooled   = ws;                      // 256 floats
    float*    bias_eff = ws + 256;                // 128 floats
    unsigned* wpk      = (unsigned*)(ws + 512);   // 32768 dwords (f16 pairs)

    pool_kernel<<<dim3(B_ * CIN), dim3(1024), 0, stream>>>(x, pooled);
    attn_weights_kernel<<<dim3(B_), dim3(256), 0, stream>>>(
        pooled, weight, bias, fc1_w, fc2_w, fc2_b, bn_g, bn_b, bn_m, bn_v,
        (unsigned short*)wpk, bias_eff);
    conv_kernel<<<dim3(128, B_), dim3(256), 0, stream>>>(
        x, wpk, bias_eff, out);
}

// Round 12
// 81.636 us; speedup vs baseline: 1.4155x; 1.4155x over previous
//
#include <hip/hip_runtime.h>
#include <hip/hip_bf16.h>

// Problem constants
#define B_  8
#define CIN 32
#define COUT 16
#define K_  4
#define HID 9
#define HIN 256
#define WIN 256
#define HW  (HIN * WIN)
#define HOUT 512
#define WOUT 512
#define TEMP 34.0f
#define EPS_ 1e-5f

#define SLAB 1168   // dwords per channel-pair slab: 34*34=1156, padded so
                    // (SLAB % 32)==16 -> lane-group aliasing 2-way (free)

typedef float f32x4 __attribute__((ext_vector_type(4)));
typedef __fp16 fp16x2 __attribute__((ext_vector_type(2)));
typedef __fp16 f16x8 __attribute__((ext_vector_type(8)));

union FragB { unsigned u[4]; f16x8 h; };

__device__ inline unsigned pk2(float a, float b) {
    union { fp16x2 f; unsigned u; } x;
    x.f = __builtin_amdgcn_cvt_pkrtz(a, b);  // a -> low half, b -> high half
    return x.u;
}
__device__ inline unsigned short f16b(float v) {
    union { __fp16 h; unsigned short u; } x;
    x.h = (__fp16)v;
    return x.u;
}

// ---------------------------------------------------------------------------
// Kernel A: pooled[b][c] = mean over HxW of x[b][c]  (== mean of upsampled)
// ---------------------------------------------------------------------------
__global__ __launch_bounds__(1024) void pool_kernel(const float* __restrict__ x,
                                                    float* __restrict__ pooled) {
    int bc = blockIdx.x;  // 0..255  (b*32+c)
    const float4* p = (const float4*)(x + (size_t)bc * HW);
    float s = 0.f;
    for (int i = threadIdx.x; i < HW / 4; i += 1024) {
        float4 v = p[i];
        s += v.x + v.y + v.z + v.w;
    }
    #pragma unroll
    for (int off = 32; off > 0; off >>= 1) s += __shfl_down(s, off);
    __shared__ float red[16];
    if ((threadIdx.x & 63) == 0) red[threadIdx.x >> 6] = s;
    __syncthreads();
    if (threadIdx.x < 16) {
        float t = red[threadIdx.x];
        t += __shfl_down(t, 8);
        t += __shfl_down(t, 4);
        t += __shfl_down(t, 2);
        t += __shfl_down(t, 1);
        if (threadIdx.x == 0) pooled[bc] = t * (1.f / HW);
    }
}

// ---------------------------------------------------------------------------
// Kernel B: attention -> aggregated, BN-folded, parity-combined 2x2 weights,
// packed f16 in the MFMA A-fragment layout (same as R8..R11, verified):
// ushort index = (((b*16 + par*4 + ks)*64 + (g*16+o))*4 + tap)*2 + (i&1)
// ---------------------------------------------------------------------------
__global__ __launch_bounds__(256) void attn_weights_kernel(
    const float* __restrict__ pooled, const float* __restrict__ weight,
    const float* __restrict__ bias, const float* __restrict__ fc1_w,
    const float* __restrict__ fc2_w, const float* __restrict__ fc2_b,
    const float* __restrict__ gamma, const float* __restrict__ beta,
    const float* __restrict__ mean, const float* __restrict__ var,
    unsigned short* __restrict__ wpk16, float* __restrict__ bias_eff) {
    int b = blockIdx.x;
    __shared__ float attn[K_];
    if (threadIdx.x == 0) {
        const float* pb = pooled + b * CIN;
        float h[HID];
        for (int j = 0; j < HID; ++j) {
            float s = 0.f;
            for (int c = 0; c < CIN; ++c) s += pb[c] * fc1_w[j * CIN + c];
            h[j] = fmaxf(s, 0.f);
        }
        float lg[K_];
        float mx = -1e30f;
        for (int k = 0; k < K_; ++k) {
            float s = fc2_b[k];
            for (int j = 0; j < HID; ++j) s += h[j] * fc2_w[k * HID + j];
            lg[k] = s * (1.f / TEMP);
            mx = fmaxf(mx, lg[k]);
        }
        float den = 0.f;
        for (int k = 0; k < K_; ++k) { lg[k] = expf(lg[k] - mx); den += lg[k]; }
        for (int k = 0; k < K_; ++k) attn[k] = lg[k] / den;
    }
    __syncthreads();
    float a0 = attn[0], a1 = attn[1], a2 = attn[2], a3v = attn[3];

    for (int p = threadIdx.x; p < COUT * CIN; p += 256) {
        int o = p >> 5, i = p & 31;
        float scale = gamma[o] / sqrtf(var[o] + EPS_);
        const float* w0 = weight + ((size_t)(0 * COUT + o) * CIN + i) * 9;
        const int kstr = COUT * CIN * 9;  // 4608
        float a3w[9];
        #pragma unroll
        for (int t = 0; t < 9; ++t)
            a3w[t] = scale * (a0 * w0[t] + a1 * w0[kstr + t] +
                              a2 * w0[2 * kstr + t] + a3v * w0[3 * kstr + t]);
        float tmp[2][2][3];
        #pragma unroll
        for (int kx = 0; kx < 3; ++kx) {
            tmp[0][0][kx] = a3w[0 * 3 + kx];
            tmp[0][1][kx] = a3w[1 * 3 + kx] + a3w[2 * 3 + kx];
            tmp[1][0][kx] = a3w[0 * 3 + kx] + a3w[1 * 3 + kx];
            tmp[1][1][kx] = a3w[2 * 3 + kx];
        }
        float w16[16];  // [par(py,px)][tap(u,v)] = [par*4 + u*2+v]
        #pragma unroll
        for (int py = 0; py < 2; ++py)
            #pragma unroll
            for (int px = 0; px < 2; ++px)
                #pragma unroll
                for (int u = 0; u < 2; ++u)
                    #pragma unroll
                    for (int v = 0; v < 2; ++v) {
                        const float* t = tmp[py][u];
                        float val = (px == 0) ? (v == 0 ? t[0] : t[1] + t[2])
                                              : (v == 0 ? t[0] + t[1] : t[2]);
                        w16[(py * 2 + px) * 4 + u * 2 + v] = val;
                    }
        const int ks = i >> 3, g = (i >> 1) & 3, hf = i & 1;
        const int l = g * 16 + o;
        #pragma unroll
        for (int par = 0; par < 4; ++par)
            #pragma unroll
            for (int d = 0; d < 4; ++d)
                wpk16[(((size_t)(b * 16 + par * 4 + ks) * 64 + l) * 4 + d) * 2 +
                      hf] = f16b(w16[par * 4 + d]);
    }
    if (threadIdx.x < COUT) {
        int o = threadIdx.x;
        float scale = gamma[o] / sqrtf(var[o] + EPS_);
        float shift = beta[o] - mean[o] * scale;
        float s = a0 * bias[0 * COUT + o] + a1 * bias[1 * COUT + o] +
                  a2 * bias[2 * COUT + o] + a3v * bias[3 * COUT + o];
        bias_eff[b * COUT + o] = s * scale + shift;
    }
}

// ---------------------------------------------------------------------------
// Kernel C: fused upsample+conv+BN+ReLU via MFMA (16x16x32 f16).
// Block: (b, 32x32 input-base tile) -> 64x64 outputs x 16 o. LDS 74.75 KB.
// Stage: FIXED-TRIP fully-unrolled flat loop (16 x 5 predicated iterations,
// all loads independent -> compiler pipelines with incremental vmcnt).
// Compute: wave owns 8 base rows; per (half, row-pair, K-step): 12 ds_read
// window feeds 2 rows x 4 parity MFMAs (acc[2][4] = 32 VGPRs, transient).
// ---------------------------------------------------------------------------
__global__ __launch_bounds__(256) void conv_kernel(
    const float* __restrict__ x, const unsigned* __restrict__ wpk,
    const float* __restrict__ bias_eff, float* __restrict__ out) {
    const int tile = blockIdx.x;   // 0..63
    const int b = blockIdx.y;      // 0..7
    const int r0 = (tile >> 3) * 32, c0 = (tile & 7) * 32;
    const int tid = threadIdx.x;

    __shared__ unsigned lds32[16 * SLAB];  // 74,752 B

    const int w = tid >> 6, lane = tid & 63;
    const int g = lane >> 4, n = lane & 15;

    const float* xb = x + (size_t)b * CIN * HW;

    // ---- stage: flat unrolled, predicated; 160 independent load-pairs ----
    #pragma unroll
    for (int i2 = 0; i2 < 16; ++i2) {
        const float* p0 = xb + (size_t)(2 * i2) * HW;
        #pragma unroll
        for (int t = 0; t < 5; ++t) {
            int e = tid + t * 256;          // 0..1279
            bool live = e < 34 * 34;
            int pr = e / 34, pc = e - pr * 34;
            int gr = r0 - 1 + pr, gc = c0 - 1 + pc;
            bool ok = live & ((unsigned)gr < (unsigned)HIN) &
                      ((unsigned)gc < (unsigned)WIN);
            int off = ok ? (gr * WIN + gc) : 0;
            float v0 = p0[off];
            float v1 = p0[off + HW];
            if (!ok) { v0 = 0.f; v1 = 0.f; }
            if (live) lds32[i2 * SLAB + e] = pk2(v0, v1);
        }
    }

    // A fragments [par][ks]: issue after staging stores; latency overlaps
    // the barrier drain below.
    f16x8 areg[4][4];
    {
        const f16x8* wp = (const f16x8*)wpk + (size_t)b * 1024 + lane;
        #pragma unroll
        for (int par = 0; par < 4; ++par)
            #pragma unroll
            for (int ks = 0; ks < 4; ++ks)
                areg[par][ks] = wp[(par * 4 + ks) * 64];
    }
    float bias4[4];
    #pragma unroll
    for (int q = 0; q < 4; ++q) bias4[q] = bias_eff[b * COUT + g * 4 + q];

    __syncthreads();

    // wave w owns base rows w*8 .. w*8+7: 2 column halves x 4 row pairs
    for (int h = 0; h < 2; ++h) {
        #pragma unroll
        for (int p2 = 0; p2 < 4; ++p2) {
            const int rA = w * 8 + p2 * 2;  // first base row of the pair

            f32x4 acc[2][4];
            #pragma unroll
            for (int rr = 0; rr < 2; ++rr)
                #pragma unroll
                for (int par = 0; par < 4; ++par)
                    acc[rr][par] = (f32x4){0.f, 0.f, 0.f, 0.f};

            #pragma unroll
            for (int ks = 0; ks < 4; ++ks) {
                const int base = (ks * 4 + g) * SLAB + rA * 34 + (h << 4) + n;
                unsigned nb[4][3];  // 4-row x 3-col window, shared by 2 rows
                #pragma unroll
                for (int rr = 0; rr < 4; ++rr)
                    #pragma unroll
                    for (int dv = 0; dv < 3; ++dv)
                        nb[rr][dv] = lds32[base + rr * 34 + dv];
                #pragma unroll
                for (int rr = 0; rr < 2; ++rr)
                    #pragma unroll
                    for (int par = 0; par < 4; ++par) {
                        const int py = par >> 1, px = par & 1;
                        FragB bf;
                        bf.u[0] = nb[rr + py][px];
                        bf.u[1] = nb[rr + py][px + 1];
                        bf.u[2] = nb[rr + py + 1][px];
                        bf.u[3] = nb[rr + py + 1][px + 1];
                        acc[rr][par] = __builtin_amdgcn_mfma_f32_16x16x32_f16(
                            areg[par][ks], bf.h, acc[rr][par], 0, 0, 0);
                    }
            }

            // epilogue: bias + ReLU, px-paired float2 stores
            #pragma unroll
            for (int rr = 0; rr < 2; ++rr) {
                #pragma unroll
                for (int py = 0; py < 2; ++py) {
                    const int y = 2 * (r0 + rA + rr) + py;
                    #pragma unroll
                    for (int q = 0; q < 4; ++q) {
                        float2 st;
                        st.x = fmaxf(acc[rr][2 * py + 0][q] + bias4[q], 0.f);
                        st.y = fmaxf(acc[rr][2 * py + 1][q] + bias4[q], 0.f);
                        *(float2*)&out[((size_t)(b * COUT + g * 4 + q) * HOUT +
                                        y) * WOUT +
                                       2 * (c0 + (h << 4) + n)] = st;
                    }
                }
            }
        }
    }
}

extern "C" void kernel_launch(void* const* d_in, const int* in_sizes, int n_in,
                              void* d_out, int out_size, void* d_ws, size_t ws_size,
                              hipStream_t stream) {
    const float* x      = (const float*)d_in[0];
    const float* weight = (const float*)d_in[1];
    const float* bias   = (const float*)d_in[2];
    const float* fc1_w  = (const float*)d_in[3];
    const float* fc2_w  = (const float*)d_in[4];
    const float* fc2_b  = (const float*)d_in[5];
    const float* bn_g   = (const float*)d_in[6];
    const float* bn_b   = (const float*)d_in[7];
    const float* bn_m   = (const float*)d_in[8];
    const float* bn_v   = (const float*)d_in[9];
    float* out = (float*)d_out;

    float* ws = (float*)d_ws;
    float*    pooled   = ws;                      // 256 floats
    float*    bias_eff = ws + 256;                // 128 floats
    unsigned* wpk      = (unsigned*)(ws + 512);   // 32768 dwords (f16 pairs)

    pool_kernel<<<dim3(B_ * CIN), dim3(1024), 0, stream>>>(x, pooled);
    attn_weights_kernel<<<dim3(B_), dim3(256), 0, stream>>>(
        pooled, weight, bias, fc1_w, fc2_w, fc2_b, bn_g, bn_b, bn_m, bn_v,
        (unsigned short*)wpk, bias_eff);
    conv_kernel<<<dim3(64, B_), dim3(256), 0, stream>>>(
        x, wpk, bias_eff, out);
}